// Round 7
// baseline (61.345 us; speedup 1.0000x reference)
//
#include <hip/hip_runtime.h>
#include <hip/hip_bf16.h>

// ---------------- constants ----------------
#define B_SZ 2
#define L_SZ 512
#define D_MODEL 512
#define D_INNER 1024
#define HEAD_DIM 64
#define NHEADS 16
#define D_STATE 64
#define D_CONV 3
#define CONV_DIM 1152            // D_INNER + 2*D_STATE
#define D_IN_PROJ 2192           // 2*D_INNER + 2*D_STATE + NHEADS
#define BL (B_SZ * L_SZ)         // 1024
#define RMS_EPS 1e-5f
#define QC 64                    // SSD chunk length
#define NCH 8                    // chunks per batch (L_SZ/QC)
#define NPAD1 2304               // W_in^T padded rows (36*64)
#define PB 72                    // bf16 LDS pitch (144B rows: frag reads 2-way = free)

typedef __attribute__((ext_vector_type(8))) short short8t;
typedef __attribute__((ext_vector_type(8))) unsigned short ushort8t;
typedef __attribute__((ext_vector_type(4))) unsigned short ushort4t;
typedef __attribute__((ext_vector_type(4))) float f32x4;

__device__ __forceinline__ unsigned short f2bf(float f) {
    unsigned u = __float_as_uint(f);
    u += 0x7fff + ((u >> 16) & 1);          // round-to-nearest-even
    return (unsigned short)(u >> 16);
}
__device__ __forceinline__ float bf2f(unsigned short u) {
    return __uint_as_float(((unsigned)u) << 16);
}

__device__ __forceinline__ void gload_lds16(const void* g, void* lds) {
    __builtin_amdgcn_global_load_lds(
        (const __attribute__((address_space(1))) unsigned int*)g,
        (__attribute__((address_space(3))) unsigned int*)lds, 16, 0, 0);
}

// ---------------- prep: W_in -> Wt1[2304][512], W_out(*rms_w) -> Wt2[512][1024], u -> bf16
__device__ __forceinline__ void transpose_tile_bf16(const float* __restrict__ src,
                                                    const float* __restrict__ scale,
                                                    unsigned short* __restrict__ dst,
                                                    int K, int Nin, int tile, int ntn) {
    __shared__ float T[64][65];
    int tid = threadIdx.x;
    int nt = tile % ntn, kt = tile / ntn;
    int n0 = nt * 64, k0 = kt * 64;
#pragma unroll
    for (int rr = 0; rr < 4; ++rr) {
        int k = k0 + (tid >> 4) + rr * 16;
        float sc = scale ? scale[k] : 1.f;
        int nn = (tid & 15) * 4;
#pragma unroll
        for (int q = 0; q < 4; ++q) {
            int n = n0 + nn + q;
            T[(tid >> 4) + rr * 16][nn + q] = (n < Nin) ? src[(size_t)k * Nin + n] * sc : 0.f;
        }
    }
    __syncthreads();
    int nn2 = tid >> 2, kc = tid & 3;
    unsigned short ov[16];
#pragma unroll
    for (int j = 0; j < 16; ++j) ov[j] = f2bf(T[kc * 16 + j][nn2]);
    unsigned short* p = dst + (size_t)(n0 + nn2) * K + k0 + kc * 16;
    *(ushort8t*)p = *(ushort8t*)&ov[0];
    *(ushort8t*)(p + 8) = *(ushort8t*)&ov[8];
}

__global__ __launch_bounds__(256) void prep_kernel(const float* __restrict__ W_in,
                                                   const float* __restrict__ W_out,
                                                   const float* __restrict__ rms_w,
                                                   const float* __restrict__ u,
                                                   unsigned short* __restrict__ Wt1,
                                                   unsigned short* __restrict__ Wt2,
                                                   unsigned short* __restrict__ u_bf) {
    int bid = blockIdx.x;
    if (bid < 288) {
        transpose_tile_bf16(W_in, nullptr, Wt1, D_MODEL, D_IN_PROJ, bid, 36);
    } else if (bid < 416) {
        transpose_tile_bf16(W_out, rms_w, Wt2, D_INNER, D_MODEL, bid - 288, 8);
    } else {
        int i = ((bid - 416) * 256 + threadIdx.x) * 8;
        float4 v0 = *(const float4*)(u + i);
        float4 v1 = *(const float4*)(u + i + 4);
        unsigned short ov[8] = {f2bf(v0.x), f2bf(v0.y), f2bf(v0.z), f2bf(v0.w),
                                f2bf(v1.x), f2bf(v1.y), f2bf(v1.z), f2bf(v1.w)};
        *(ushort8t*)(u_bf + i) = *(ushort8t*)&ov[0];
    }
}

// ---------------- bf16 MFMA GEMM (in_proj): C[M,N] = A[M,K] * Bt[N,K]^T ----------------
__global__ __launch_bounds__(256) void gemm_mfma64(const unsigned short* __restrict__ A,
                                                   const unsigned short* __restrict__ Bt,
                                                   float* __restrict__ C,
                                                   int N, int K) {
    __shared__ char sm[49152];          // 3 buf x (A:8192 | B:8192)
    int tid = threadIdx.x;
    int w = tid >> 6, l = tid & 63;
    int m0 = blockIdx.y * 64, n0 = blockIdx.x * 64;
    int wm = w >> 1, wn = w & 1;

    f32x4 acc[2][2];
#pragma unroll
    for (int i = 0; i < 2; ++i)
#pragma unroll
        for (int j = 0; j < 2; ++j) acc[i][j] = (f32x4){0.f, 0.f, 0.f, 0.f};

    auto stage = [&](const unsigned short* src, int row0, int k0, char* dst) {
#pragma unroll
        for (int p = 0; p < 2; ++p) {
            int c = w * 2 + p;
            int row = c * 8 + (l >> 3);
            int scb = ((l & 7) << 4) ^ ((row & 7) << 4);
            gload_lds16(src + (size_t)(row0 + row) * K + k0 + (scb >> 1), dst + c * 1024);
        }
    };

    int nkt = K / 64;
    stage(A, m0, 0, sm);
    stage(Bt, n0, 0, sm + 8192);
    if (nkt > 1) {
        stage(A, m0, 64, sm + 16384);
        stage(Bt, n0, 64, sm + 16384 + 8192);
    }

    for (int kt = 0; kt < nkt; ++kt) {
        if (kt + 2 < nkt) {
            char* d = sm + ((kt + 2) % 3) * 16384;
            stage(A, m0, (kt + 2) * 64, d);
            stage(Bt, n0, (kt + 2) * 64, d + 8192);
        }
        int inflight = nkt - 1 - kt;
        if (inflight >= 2)      asm volatile("s_waitcnt vmcnt(8)" ::: "memory");
        else if (inflight == 1) asm volatile("s_waitcnt vmcnt(4)" ::: "memory");
        else                    asm volatile("s_waitcnt vmcnt(0)" ::: "memory");
        __builtin_amdgcn_s_barrier();

        const char* Ab = sm + (kt % 3) * 16384;
        const char* Bb = Ab + 8192;
#pragma unroll
        for (int kk = 0; kk < 2; ++kk) {
            short8t af[2], bf[2];
#pragma unroll
            for (int i = 0; i < 2; ++i) {
                int r = wm * 32 + i * 16 + (l & 15);
                int cb = (kk * 64 + (l >> 4) * 16) ^ ((r & 7) << 4);
                af[i] = *(const short8t*)(Ab + r * 128 + cb);
            }
#pragma unroll
            for (int j = 0; j < 2; ++j) {
                int r = wn * 32 + j * 16 + (l & 15);
                int cb = (kk * 64 + (l >> 4) * 16) ^ ((r & 7) << 4);
                bf[j] = *(const short8t*)(Bb + r * 128 + cb);
            }
#pragma unroll
            for (int i = 0; i < 2; ++i)
#pragma unroll
                for (int j = 0; j < 2; ++j)
                    acc[i][j] = __builtin_amdgcn_mfma_f32_16x16x32_bf16(af[i], bf[j], acc[i][j], 0, 0, 0);
        }
        __builtin_amdgcn_s_barrier();
    }

#pragma unroll
    for (int i = 0; i < 2; ++i)
#pragma unroll
        for (int j = 0; j < 2; ++j) {
            int row = m0 + wm * 32 + i * 16 + (l >> 4) * 4;
            int col = n0 + wn * 32 + j * 16 + (l & 15);
            if (col < N) {
#pragma unroll
                for (int r = 0; r < 4; ++r)
                    C[(size_t)(row + r) * N + col] = acc[i][j][r];
            }
        }
}

// conv+SiLU of 4 consecutive channels at one row; gl = seq position (causal clamp)
__device__ __forceinline__ float4 conv4(const float* __restrict__ prow, int gl, int zxcol,
                                        const float* __restrict__ conv_w,
                                        const float* __restrict__ conv_b) {
    float4 v2 = *(const float4*)(prow + zxcol);
    float4 v1 = make_float4(0.f, 0.f, 0.f, 0.f), v0 = v1;
    if (gl >= 1) v1 = *(const float4*)(prow - D_IN_PROJ + zxcol);
    if (gl >= 2) v0 = *(const float4*)(prow - 2 * D_IN_PROJ + zxcol);
    int ch = zxcol - D_INNER;
    float4 o;
    float a;
    a = conv_b[ch+0] + conv_w[(ch+0)*3]*v0.x + conv_w[(ch+0)*3+1]*v1.x + conv_w[(ch+0)*3+2]*v2.x;
    o.x = a / (1.f + __expf(-a));
    a = conv_b[ch+1] + conv_w[(ch+1)*3]*v0.y + conv_w[(ch+1)*3+1]*v1.y + conv_w[(ch+1)*3+2]*v2.y;
    o.y = a / (1.f + __expf(-a));
    a = conv_b[ch+2] + conv_w[(ch+2)*3]*v0.z + conv_w[(ch+2)*3+1]*v1.z + conv_w[(ch+2)*3+2]*v2.z;
    o.z = a / (1.f + __expf(-a));
    a = conv_b[ch+3] + conv_w[(ch+3)*3]*v0.w + conv_w[(ch+3)*3+1]*v1.w + conv_w[(ch+3)*3+2]*v2.w;
    o.w = a / (1.f + __expf(-a));
    return o;
}

// ---------------- SSD pass A (conv fused, MFMA matmuls) ----------------
__global__ __launch_bounds__(256) void ssd_passA(const float* __restrict__ zxbcdt,
                                                 const float* __restrict__ conv_w,
                                                 const float* __restrict__ conv_b,
                                                 const float* __restrict__ dt_bias,
                                                 const float* __restrict__ A_log,
                                                 const float* __restrict__ D_param,
                                                 float* __restrict__ y,
                                                 float* __restrict__ Zbuf,
                                                 float* __restrict__ Ebuf) {
    int blk = blockIdx.x;          // b*128 + c*16 + h
    int h = blk & 15;
    int c = (blk >> 4) & 7;
    int b = blk >> 7;
    int tid = threadIdx.x;

    __shared__ __align__(16) unsigned short Cs_bf[QC][PB];   // C[t][n]
    __shared__ __align__(16) unsigned short Bs_bf[QC][PB];   // B[s][n]
    __shared__ __align__(16) unsigned short BT_bf[QC][PB];   // B^T[n][t]
    __shared__ __align__(16) unsigned short XDT_bf[QC][PB];  // XD^T[p][t]
    __shared__ __align__(16) unsigned short XDTw_bf[QC][PB]; // (w·XD)^T[p][t]
    __shared__ __align__(16) unsigned short P_bf[QC][PB];    // P[t][s]
    __shared__ float csh[QC], dts[QC], wh[QC];

    int bl0 = b * L_SZ + c * QC;
    const float* zb = zxbcdt + (size_t)bl0 * D_IN_PROJ;

    if (tid < 64) {
        int t = tid;
        float draw = zb[(size_t)t * D_IN_PROJ + 2 * D_INNER + 2 * D_STATE + h];
        float dtv = draw + dt_bias[h];
        dtv = (dtv > 20.f) ? dtv : log1pf(expf(dtv));
        float A = -expf(A_log[h]);
        float cs = A * dtv;
#pragma unroll
        for (int off = 1; off < 64; off <<= 1) {
            float tmp = __shfl_up(cs, off);
            if (t >= off) cs += tmp;
        }
        float cs63 = __shfl(cs, 63);
        dts[t] = dtv;
        csh[t] = cs;
        wh[t] = __expf(cs63 - cs);
        Ebuf[(((size_t)(b * NHEADS + h) * NCH) + c) * QC + t] = __expf(cs);
    }

    int row16 = tid >> 4;
    int col4 = (tid & 15) * 4;
#pragma unroll
    for (int r = 0; r < 4; ++r) {
        int t = r * 16 + row16;
        int gl = c * QC + t;
        const float* prow = zb + (size_t)t * D_IN_PROJ;
        float4 Bv = conv4(prow, gl, D_INNER + D_INNER + col4, conv_w, conv_b);
        float4 Cv = conv4(prow, gl, D_INNER + D_INNER + D_STATE + col4, conv_w, conv_b);
        ushort4t bq = {f2bf(Bv.x), f2bf(Bv.y), f2bf(Bv.z), f2bf(Bv.w)};
        ushort4t cq = {f2bf(Cv.x), f2bf(Cv.y), f2bf(Cv.z), f2bf(Cv.w)};
        *(ushort4t*)&Bs_bf[t][col4] = bq;
        *(ushort4t*)&Cs_bf[t][col4] = cq;
#pragma unroll
        for (int q = 0; q < 4; ++q) BT_bf[col4 + q][t] = bq[q];
    }
    __syncthreads();

#pragma unroll
    for (int r = 0; r < 4; ++r) {
        int t = r * 16 + row16;
        int gl = c * QC + t;
        const float* prow = zb + (size_t)t * D_IN_PROJ;
        float4 xv = conv4(prow, gl, D_INNER + h * HEAD_DIM + col4, conv_w, conv_b);
        float d = dts[t], wt = wh[t];
        xv.x *= d; xv.y *= d; xv.z *= d; xv.w *= d;
        ushort4t xq = {f2bf(xv.x), f2bf(xv.y), f2bf(xv.z), f2bf(xv.w)};
        ushort4t xwq = {f2bf(xv.x * wt), f2bf(xv.y * wt), f2bf(xv.z * wt), f2bf(xv.w * wt)};
#pragma unroll
        for (int q = 0; q < 4; ++q) {
            XDT_bf[col4 + q][t] = xq[q];
            XDTw_bf[col4 + q][t] = xwq[q];
        }
    }

    int l = tid & 63, wv = tid >> 6;
    int wm = wv >> 1, wn = wv & 1;
    int fr = l & 15, fq = l >> 4;

    {   // G = C·B^T via MFMA, mask+decay -> P_bf
        f32x4 g[2][2];
#pragma unroll
        for (int i = 0; i < 2; ++i)
#pragma unroll
            for (int j = 0; j < 2; ++j) g[i][j] = (f32x4){0.f, 0.f, 0.f, 0.f};
#pragma unroll
        for (int kk = 0; kk < 2; ++kk) {
            short8t af[2], bb[2];
#pragma unroll
            for (int i = 0; i < 2; ++i)
                af[i] = *(const short8t*)&Cs_bf[wm * 32 + i * 16 + fr][kk * 32 + fq * 8];
#pragma unroll
            for (int j = 0; j < 2; ++j)
                bb[j] = *(const short8t*)&Bs_bf[wn * 32 + j * 16 + fr][kk * 32 + fq * 8];
#pragma unroll
            for (int i = 0; i < 2; ++i)
#pragma unroll
                for (int j = 0; j < 2; ++j)
                    g[i][j] = __builtin_amdgcn_mfma_f32_16x16x32_bf16(af[i], bb[j], g[i][j], 0, 0, 0);
        }
#pragma unroll
        for (int i = 0; i < 2; ++i)
#pragma unroll
            for (int j = 0; j < 2; ++j) {
                int s = wn * 32 + j * 16 + fr;
                float css = csh[s];
#pragma unroll
                for (int r = 0; r < 4; ++r) {
                    int t = wm * 32 + i * 16 + fq * 4 + r;
                    float v = (s <= t) ? g[i][j][r] * __expf(csh[t] - css) : 0.f;
                    P_bf[t][s] = f2bf(v);
                }
            }
    }
    __syncthreads();

    {   // Y = P·XD via MFMA; epilogue + D·x
        f32x4 yv[2][2];
#pragma unroll
        for (int i = 0; i < 2; ++i)
#pragma unroll
            for (int j = 0; j < 2; ++j) yv[i][j] = (f32x4){0.f, 0.f, 0.f, 0.f};
#pragma unroll
        for (int kk = 0; kk < 2; ++kk) {
            short8t af[2], bb[2];
#pragma unroll
            for (int i = 0; i < 2; ++i)
                af[i] = *(const short8t*)&P_bf[wm * 32 + i * 16 + fr][kk * 32 + fq * 8];
#pragma unroll
            for (int j = 0; j < 2; ++j)
                bb[j] = *(const short8t*)&XDT_bf[wn * 32 + j * 16 + fr][kk * 32 + fq * 8];
#pragma unroll
            for (int i = 0; i < 2; ++i)
#pragma unroll
                for (int j = 0; j < 2; ++j)
                    yv[i][j] = __builtin_amdgcn_mfma_f32_16x16x32_bf16(af[i], bb[j], yv[i][j], 0, 0, 0);
        }
        float Dp = D_param[h];
#pragma unroll
        for (int i = 0; i < 2; ++i)
#pragma unroll
            for (int j = 0; j < 2; ++j) {
                int p = wn * 32 + j * 16 + fr;
#pragma unroll
                for (int r = 0; r < 4; ++r) {
                    int t = wm * 32 + i * 16 + fq * 4 + r;
                    float xval = bf2f(XDT_bf[p][t]);
                    float fct = Dp / dts[t];
                    y[(size_t)(bl0 + t) * D_INNER + h * HEAD_DIM + p] =
                        yv[i][j][r] + fct * xval;
                }
            }
    }

    {   // Z = (w·XD)^T·B via MFMA -> Zbuf
        f32x4 zv[2][2];
#pragma unroll
        for (int i = 0; i < 2; ++i)
#pragma unroll
            for (int j = 0; j < 2; ++j) zv[i][j] = (f32x4){0.f, 0.f, 0.f, 0.f};
#pragma unroll
        for (int kk = 0; kk < 2; ++kk) {
            short8t af[2], bb[2];
#pragma unroll
            for (int i = 0; i < 2; ++i)
                af[i] = *(const short8t*)&XDTw_bf[wm * 32 + i * 16 + fr][kk * 32 + fq * 8];
#pragma unroll
            for (int j = 0; j < 2; ++j)
                bb[j] = *(const short8t*)&BT_bf[wn * 32 + j * 16 + fr][kk * 32 + fq * 8];
#pragma unroll
            for (int i = 0; i < 2; ++i)
#pragma unroll
                for (int j = 0; j < 2; ++j)
                    zv[i][j] = __builtin_amdgcn_mfma_f32_16x16x32_bf16(af[i], bb[j], zv[i][j], 0, 0, 0);
        }
        float* Zr = Zbuf + (((size_t)(b * NHEADS + h) * NCH) + c) * (HEAD_DIM * D_STATE);
#pragma unroll
        for (int i = 0; i < 2; ++i)
#pragma unroll
            for (int j = 0; j < 2; ++j) {
                int n = wn * 32 + j * 16 + fr;
#pragma unroll
                for (int r = 0; r < 4; ++r) {
                    int p = wm * 32 + i * 16 + fq * 4 + r;
                    Zr[p * D_STATE + n] = zv[i][j][r];
                }
            }
    }
}

// ---------------- SSD pass C (passB folded; 224 blocks, c>=1 only) ----------------
__global__ __launch_bounds__(256) void ssd_passC(const float* __restrict__ zxbcdt,
                                                 const float* __restrict__ conv_w,
                                                 const float* __restrict__ conv_b,
                                                 const float* __restrict__ Zbuf,
                                                 const float* __restrict__ Ebuf,
                                                 float* __restrict__ y) {
    int blk = blockIdx.x;          // 224 = 16h * 7c * 2b
    int h = blk & 15;
    int q = blk >> 4;              // 0..13
    int c = 1 + (q % 7);
    int b = q / 7;
    int tid = threadIdx.x;

    __shared__ __align__(16) unsigned short Cs_bf[QC][PB];
    __shared__ __align__(16) unsigned short S_bf[QC][PB];
    __shared__ float Eh[QC];

    int bl0 = b * L_SZ + c * QC;
    const float* zb = zxbcdt + (size_t)bl0 * D_IN_PROJ;
    const float* Zb = Zbuf + ((size_t)(b * NHEADS + h) * NCH) * (HEAD_DIM * D_STATE);
    const float* Eb = Ebuf + ((size_t)(b * NHEADS + h) * NCH) * QC;

    {
        int p = tid >> 2, nq = (tid & 3) * 16;
        float S16[16];
#pragma unroll
        for (int qq = 0; qq < 16; ++qq) S16[qq] = 0.f;
        float wgt = 1.f;
        for (int j = c - 1; j >= 0; --j) {
            const float* Zj = Zb + (size_t)j * (HEAD_DIM * D_STATE) + p * D_STATE + nq;
#pragma unroll
            for (int q4 = 0; q4 < 4; ++q4) {
                float4 z = *(const float4*)(Zj + q4 * 4);
                S16[q4 * 4 + 0] += wgt * z.x;
                S16[q4 * 4 + 1] += wgt * z.y;
                S16[q4 * 4 + 2] += wgt * z.z;
                S16[q4 * 4 + 3] += wgt * z.w;
            }
            wgt *= Eb[(size_t)j * QC + 63];
        }
#pragma unroll
        for (int q4 = 0; q4 < 4; ++q4) {
            ushort4t s4 = {f2bf(S16[q4 * 4 + 0]), f2bf(S16[q4 * 4 + 1]),
                           f2bf(S16[q4 * 4 + 2]), f2bf(S16[q4 * 4 + 3])};
            *(ushort4t*)&S_bf[p][nq + q4 * 4] = s4;
        }
    }

    int row16 = tid >> 4, col4 = (tid & 15) * 4;
#pragma unroll
    for (int r = 0; r < 4; ++r) {
        int t = r * 16 + row16;
        int gl = c * QC + t;
        float4 Cv = conv4(zb + (size_t)t * D_IN_PROJ, gl,
                          D_INNER + D_INNER + D_STATE + col4, conv_w, conv_b);
        ushort4t cq = {f2bf(Cv.x), f2bf(Cv.y), f2bf(Cv.z), f2bf(Cv.w)};
        *(ushort4t*)&Cs_bf[t][col4] = cq;
    }
    if (tid < 64)
        Eh[tid] = Ebuf[(((size_t)(b * NHEADS + h) * NCH) + c) * QC + tid];
    __syncthreads();

    int l = tid & 63, wv = tid >> 6;
    int wm = wv >> 1, wn = wv & 1;
    int fr = l & 15, fq = l >> 4;
    f32x4 acc[2][2];
#pragma unroll
    for (int i = 0; i < 2; ++i)
#pragma unroll
        for (int j = 0; j < 2; ++j) acc[i][j] = (f32x4){0.f, 0.f, 0.f, 0.f};
#pragma unroll
    for (int kk = 0; kk < 2; ++kk) {
        short8t af[2], bb[2];
#pragma unroll
        for (int i = 0; i < 2; ++i)
            af[i] = *(const short8t*)&Cs_bf[wm * 32 + i * 16 + fr][kk * 32 + fq * 8];
#pragma unroll
        for (int j = 0; j < 2; ++j)
            bb[j] = *(const short8t*)&S_bf[wn * 32 + j * 16 + fr][kk * 32 + fq * 8];
#pragma unroll
        for (int i = 0; i < 2; ++i)
#pragma unroll
            for (int j = 0; j < 2; ++j)
                acc[i][j] = __builtin_amdgcn_mfma_f32_16x16x32_bf16(af[i], bb[j], acc[i][j], 0, 0, 0);
    }
#pragma unroll
    for (int i = 0; i < 2; ++i)
#pragma unroll
        for (int j = 0; j < 2; ++j) {
            int p = wn * 32 + j * 16 + fr;
#pragma unroll
            for (int r = 0; r < 4; ++r) {
                int t = wm * 32 + i * 16 + fq * 4 + r;
                float* yp = y + (size_t)(bl0 + t) * D_INNER + h * HEAD_DIM + p;
                *yp += Eh[t] * acc[i][j][r];
            }
        }
}

// ---------------- out_proj fused with gate+RMSNorm ----------------
// out[M=1024, N=512] = rowscale( yz @ Wt2'^T ), yz = y*silu(z), Wt2' has rms_w folded.
// 32x64 tile, 256 blocks. A reg-staged (T14 split), B via gload_lds. 2-buf LDS.
__global__ __launch_bounds__(256) void gemm_out_fused(const float* __restrict__ y,
                                                      const float* __restrict__ zxbcdt,
                                                      const unsigned short* __restrict__ Bt,
                                                      float* __restrict__ out) {
    __shared__ char sm[2][12288];      // per buf: A(32x64 bf16 = 4KB) @0 | B(8KB) @4096
    __shared__ float red[32][8];
    __shared__ float srow[32];
    int tid = threadIdx.x;
    int w = tid >> 6, l = tid & 63;
    int m0 = blockIdx.y * 32, n0 = blockIdx.x * 64;
    int wm = w >> 1, wn = w & 1;

    f32x4 acc[2];
    acc[0] = (f32x4){0.f, 0.f, 0.f, 0.f};
    acc[1] = (f32x4){0.f, 0.f, 0.f, 0.f};

    int ar = tid >> 3, ac8 = tid & 7;                 // A: row 0..31, k-octet 0..7
    const float* yrow = y + (size_t)(m0 + ar) * D_INNER + ac8 * 8;
    const float* zrow = zxbcdt + (size_t)(m0 + ar) * D_IN_PROJ + ac8 * 8;
    float sumsq = 0.f;

    auto stageB = [&](int k0, char* dstB) {
#pragma unroll
        for (int p = 0; p < 2; ++p) {
            int cc = w * 2 + p;
            int row = cc * 8 + (l >> 3);
            int scb = ((l & 7) << 4) ^ ((row & 7) << 4);
            gload_lds16(Bt + (size_t)(n0 + row) * D_INNER + k0 + (scb >> 1), dstB + cc * 1024);
        }
    };

    float4 vy0, vy1, vz0, vz1;
    auto loadA = [&](int k0) {
        vy0 = *(const float4*)(yrow + k0);
        vy1 = *(const float4*)(yrow + k0 + 4);
        vz0 = *(const float4*)(zrow + k0);
        vz1 = *(const float4*)(zrow + k0 + 4);
    };
    auto writeA = [&](char* dstA) {
        float yv[8] = {vy0.x, vy0.y, vy0.z, vy0.w, vy1.x, vy1.y, vy1.z, vy1.w};
        float zv[8] = {vz0.x, vz0.y, vz0.z, vz0.w, vz1.x, vz1.y, vz1.z, vz1.w};
        unsigned short o[8];
#pragma unroll
        for (int qq = 0; qq < 8; ++qq) {
            float vv = yv[qq] * (zv[qq] / (1.f + __expf(-zv[qq])));
            sumsq += vv * vv;
            o[qq] = f2bf(vv);
        }
        int b0 = ac8 * 16;
        *(ushort8t*)(dstA + ar * 128 + (b0 ^ ((ar & 7) << 4))) = *(ushort8t*)o;
    };

    // prologue: tile 0
    loadA(0);
    stageB(0, sm[0] + 4096);
    writeA(sm[0]);                                    // implicit wait on A(0) loads
    asm volatile("s_waitcnt lgkmcnt(0)" ::: "memory");

    for (int kt = 0; kt < 16; ++kt) {
        int cur = kt & 1;
        if (kt + 1 < 16) {
            loadA((kt + 1) * 64);                     // issue early (T14)
            stageB((kt + 1) * 64, sm[cur ^ 1] + 4096);
            asm volatile("s_waitcnt vmcnt(6)" ::: "memory");   // drain B(kt); leave A+B(kt+1)
        } else {
            asm volatile("s_waitcnt vmcnt(0)" ::: "memory");
        }
        __builtin_amdgcn_s_barrier();                 // buf(kt) fully resident

        const char* Ab = sm[cur];
        const char* Bb = sm[cur] + 4096;
#pragma unroll
        for (int kk = 0; kk < 2; ++kk) {
            short8t af;
            {
                int r = wm * 16 + (l & 15);
                int cb = (kk * 64 + (l >> 4) * 16) ^ ((r & 7) << 4);
                af = *(const short8t*)(Ab + r * 128 + cb);
            }
#pragma unroll
            for (int j = 0; j < 2; ++j) {
                int r = wn * 32 + j * 16 + (l & 15);
                int cb = (kk * 64 + (l >> 4) * 16) ^ ((r & 7) << 4);
                short8t bfv = *(const short8t*)(Bb + r * 128 + cb);
                acc[j] = __builtin_amdgcn_mfma_f32_16x16x32_bf16(af, bfv, acc[j], 0, 0, 0);
            }
        }
        if (kt + 1 < 16) {
            asm volatile("s_waitcnt vmcnt(2)" ::: "memory");   // A(kt+1) data arrived
            writeA((char*)sm[cur ^ 1]);
            asm volatile("s_waitcnt lgkmcnt(0)" ::: "memory");
        }
        __builtin_amdgcn_s_barrier();                 // reads(kt) done; writes(kt+1) visible
    }

    red[ar][ac8] = sumsq;
    __syncthreads();
    if (tid < 32) {
        float s = 0.f;
#pragma unroll
        for (int qq = 0; qq < 8; ++qq) s += red[tid][qq];
        srow[tid] = rsqrtf(s / (float)D_INNER + RMS_EPS);
    }
    __syncthreads();

#pragma unroll
    for (int j = 0; j < 2; ++j) {
        int col = n0 + wn * 32 + j * 16 + (l & 15);
        int rl = wm * 16 + (l >> 4) * 4;
#pragma unroll
        for (int r = 0; r < 4; ++r)
            out[(size_t)(m0 + rl + r) * D_MODEL + col] = acc[j][r] * srow[rl + r];
    }
}

// ---------------- launch ----------------
extern "C" void kernel_launch(void* const* d_in, const int* in_sizes, int n_in,
                              void* d_out, int out_size, void* d_ws, size_t ws_size,
                              hipStream_t stream) {
    const float* u       = (const float*)d_in[0];
    const float* W_in    = (const float*)d_in[1];
    const float* conv_w  = (const float*)d_in[2];
    const float* conv_b  = (const float*)d_in[3];
    const float* dt_bias = (const float*)d_in[4];
    const float* A_log   = (const float*)d_in[5];
    const float* D_param = (const float*)d_in[6];
    const float* rms_w   = (const float*)d_in[7];
    const float* W_out   = (const float*)d_in[8];
    float* out = (float*)d_out;

    float* ws = (float*)d_ws;
    float* zxbcdt = ws;                                    // [1024][2192] f32
    float* y      = zxbcdt + (size_t)BL * D_IN_PROJ;       // [1024][1024] f32
    float* Zbuf   = y + (size_t)BL * D_INNER;              // [32][8][64][64] f32
    float* Ebuf   = Zbuf + (size_t)32 * NCH * 4096;        // [32][8][64] f32
    unsigned short* u_bf  = (unsigned short*)(Ebuf + 32 * NCH * QC);   // [1024][512]
    unsigned short* Wt1   = u_bf + (size_t)BL * D_MODEL;               // [2304][512]
    unsigned short* Wt2   = Wt1 + (size_t)NPAD1 * D_MODEL;             // [512][1024]

    // 0) convert/transpose weights (+rms fold) + u to bf16
    prep_kernel<<<672, 256, 0, stream>>>(W_in, W_out, rms_w, u, Wt1, Wt2, u_bf);

    // 1) in_proj: zxbcdt = u @ W_in
    gemm_mfma64<<<dim3(NPAD1 / 64, BL / 64), 256, 0, stream>>>(
        u_bf, Wt1, zxbcdt, D_IN_PROJ, D_MODEL);

    // 2) SSD
    ssd_passA<<<B_SZ * NCH * NHEADS, 256, 0, stream>>>(
        zxbcdt, conv_w, conv_b, dt_bias, A_log, D_param, y, Zbuf, Ebuf);
    ssd_passC<<<224, 256, 0, stream>>>(
        zxbcdt, conv_w, conv_b, Zbuf, Ebuf, y);

    // 3) out_proj fused with gate+RMSNorm
    gemm_out_fused<<<dim3(D_MODEL / 64, BL / 32), 256, 0, stream>>>(
        y, zxbcdt, Wt2, out);
}

// Round 8
// 47.667 us; speedup vs baseline: 1.2869x; 1.2869x over previous
//
#include <hip/hip_runtime.h>
#include <hip/hip_bf16.h>

// ---------------- constants ----------------
#define B_SZ 2
#define L_SZ 512
#define D_MODEL 512
#define D_INNER 1024
#define HEAD_DIM 64
#define NHEADS 16
#define D_STATE 64
#define D_CONV 3
#define CONV_DIM 1152            // D_INNER + 2*D_STATE
#define D_IN_PROJ 2192           // 2*D_INNER + 2*D_STATE + NHEADS
#define BL (B_SZ * L_SZ)         // 1024
#define RMS_EPS 1e-5f
#define QC 64                    // SSD chunk length
#define NCH 8                    // chunks per batch (L_SZ/QC)
#define NPAD1 2304               // W_in^T padded rows (36*64)
#define PB 72                    // bf16 LDS pitch (144B rows: frag reads 2-way = free)

typedef __attribute__((ext_vector_type(8))) short short8t;
typedef __attribute__((ext_vector_type(8))) unsigned short ushort8t;
typedef __attribute__((ext_vector_type(4))) unsigned short ushort4t;
typedef __attribute__((ext_vector_type(4))) float f32x4;

__device__ __forceinline__ unsigned short f2bf(float f) {
    unsigned u = __float_as_uint(f);
    u += 0x7fff + ((u >> 16) & 1);          // round-to-nearest-even
    return (unsigned short)(u >> 16);
}
__device__ __forceinline__ float bf2f(unsigned short u) {
    return __uint_as_float(((unsigned)u) << 16);
}

__device__ __forceinline__ void gload_lds16(const void* g, void* lds) {
    __builtin_amdgcn_global_load_lds(
        (const __attribute__((address_space(1))) unsigned int*)g,
        (__attribute__((address_space(3))) unsigned int*)lds, 16, 0, 0);
}

// ---------------- prep: W_in -> Wt1[2304][512] bf16, W_out -> Wt2[512][1024] bf16, u -> bf16
__device__ __forceinline__ void transpose_tile_bf16(const float* __restrict__ src,
                                                    unsigned short* __restrict__ dst,
                                                    int K, int Nin, int tile, int ntn) {
    __shared__ float T[64][65];
    int tid = threadIdx.x;
    int nt = tile % ntn, kt = tile / ntn;
    int n0 = nt * 64, k0 = kt * 64;
#pragma unroll
    for (int rr = 0; rr < 4; ++rr) {
        int k = k0 + (tid >> 4) + rr * 16;
        int nn = (tid & 15) * 4;
#pragma unroll
        for (int q = 0; q < 4; ++q) {
            int n = n0 + nn + q;
            T[(tid >> 4) + rr * 16][nn + q] = (n < Nin) ? src[(size_t)k * Nin + n] : 0.f;
        }
    }
    __syncthreads();
    int nn2 = tid >> 2, kc = tid & 3;
    unsigned short ov[16];
#pragma unroll
    for (int j = 0; j < 16; ++j) ov[j] = f2bf(T[kc * 16 + j][nn2]);
    unsigned short* p = dst + (size_t)(n0 + nn2) * K + k0 + kc * 16;
    *(ushort8t*)p = *(ushort8t*)&ov[0];
    *(ushort8t*)(p + 8) = *(ushort8t*)&ov[8];
}

__global__ __launch_bounds__(256) void prep_kernel(const float* __restrict__ W_in,
                                                   const float* __restrict__ W_out,
                                                   const float* __restrict__ u,
                                                   unsigned short* __restrict__ Wt1,
                                                   unsigned short* __restrict__ Wt2,
                                                   unsigned short* __restrict__ u_bf) {
    int bid = blockIdx.x;
    if (bid < 288) {
        transpose_tile_bf16(W_in, Wt1, D_MODEL, D_IN_PROJ, bid, 36);
    } else if (bid < 416) {
        transpose_tile_bf16(W_out, Wt2, D_INNER, D_MODEL, bid - 288, 8);
    } else {
        int i = ((bid - 416) * 256 + threadIdx.x) * 8;
        float4 v0 = *(const float4*)(u + i);
        float4 v1 = *(const float4*)(u + i + 4);
        unsigned short ov[8] = {f2bf(v0.x), f2bf(v0.y), f2bf(v0.z), f2bf(v0.w),
                                f2bf(v1.x), f2bf(v1.y), f2bf(v1.z), f2bf(v1.w)};
        *(ushort8t*)(u_bf + i) = *(ushort8t*)&ov[0];
    }
}

// ---------------- bf16 MFMA GEMM 64x64 (in_proj): C[M,N] = A[M,K] * Bt[N,K]^T ----------------
__global__ __launch_bounds__(256) void gemm_mfma64(const unsigned short* __restrict__ A,
                                                   const unsigned short* __restrict__ Bt,
                                                   float* __restrict__ C,
                                                   int N, int K) {
    __shared__ char sm[49152];          // 3 buf x (A:8192 | B:8192)
    int tid = threadIdx.x;
    int w = tid >> 6, l = tid & 63;
    int m0 = blockIdx.y * 64, n0 = blockIdx.x * 64;
    int wm = w >> 1, wn = w & 1;

    f32x4 acc[2][2];
#pragma unroll
    for (int i = 0; i < 2; ++i)
#pragma unroll
        for (int j = 0; j < 2; ++j) acc[i][j] = (f32x4){0.f, 0.f, 0.f, 0.f};

    auto stage = [&](const unsigned short* src, int row0, int k0, char* dst) {
#pragma unroll
        for (int p = 0; p < 2; ++p) {
            int c = w * 2 + p;
            int row = c * 8 + (l >> 3);
            int scb = ((l & 7) << 4) ^ ((row & 7) << 4);
            gload_lds16(src + (size_t)(row0 + row) * K + k0 + (scb >> 1), dst + c * 1024);
        }
    };

    int nkt = K / 64;
    stage(A, m0, 0, sm);
    stage(Bt, n0, 0, sm + 8192);
    if (nkt > 1) {
        stage(A, m0, 64, sm + 16384);
        stage(Bt, n0, 64, sm + 16384 + 8192);
    }

    for (int kt = 0; kt < nkt; ++kt) {
        if (kt + 2 < nkt) {
            char* d = sm + ((kt + 2) % 3) * 16384;
            stage(A, m0, (kt + 2) * 64, d);
            stage(Bt, n0, (kt + 2) * 64, d + 8192);
        }
        int inflight = nkt - 1 - kt;
        if (inflight >= 2)      asm volatile("s_waitcnt vmcnt(8)" ::: "memory");
        else if (inflight == 1) asm volatile("s_waitcnt vmcnt(4)" ::: "memory");
        else                    asm volatile("s_waitcnt vmcnt(0)" ::: "memory");
        __builtin_amdgcn_s_barrier();

        const char* Ab = sm + (kt % 3) * 16384;
        const char* Bb = Ab + 8192;
#pragma unroll
        for (int kk = 0; kk < 2; ++kk) {
            short8t af[2], bf[2];
#pragma unroll
            for (int i = 0; i < 2; ++i) {
                int r = wm * 32 + i * 16 + (l & 15);
                int cb = (kk * 64 + (l >> 4) * 16) ^ ((r & 7) << 4);
                af[i] = *(const short8t*)(Ab + r * 128 + cb);
            }
#pragma unroll
            for (int j = 0; j < 2; ++j) {
                int r = wn * 32 + j * 16 + (l & 15);
                int cb = (kk * 64 + (l >> 4) * 16) ^ ((r & 7) << 4);
                bf[j] = *(const short8t*)(Bb + r * 128 + cb);
            }
#pragma unroll
            for (int i = 0; i < 2; ++i)
#pragma unroll
                for (int j = 0; j < 2; ++j)
                    acc[i][j] = __builtin_amdgcn_mfma_f32_16x16x32_bf16(af[i], bf[j], acc[i][j], 0, 0, 0);
        }
        __builtin_amdgcn_s_barrier();
    }

#pragma unroll
    for (int i = 0; i < 2; ++i)
#pragma unroll
        for (int j = 0; j < 2; ++j) {
            int row = m0 + wm * 32 + i * 16 + (l >> 4) * 4;
            int col = n0 + wn * 32 + j * 16 + (l & 15);
            if (col < N) {
#pragma unroll
                for (int r = 0; r < 4; ++r)
                    C[(size_t)(row + r) * N + col] = acc[i][j][r];
            }
        }
}

// ---------------- bf16 MFMA GEMM 32x64 (out_proj): 256 blocks ----------------
// per wave per tile: 1 A-load + 2 B-loads = 3 -> counted vmcnt 6/3/0, 3-deep.
__global__ __launch_bounds__(256) void gemm_mfma32(const unsigned short* __restrict__ A,
                                                   const unsigned short* __restrict__ Bt,
                                                   float* __restrict__ C,
                                                   int N, int K) {
    __shared__ char sm[36864];          // 3 buf x (A:4096 | B:8192)
    int tid = threadIdx.x;
    int w = tid >> 6, l = tid & 63;
    int m0 = blockIdx.y * 32, n0 = blockIdx.x * 64;
    int wm = w >> 1, wn = w & 1;

    f32x4 acc[2];
    acc[0] = (f32x4){0.f, 0.f, 0.f, 0.f};
    acc[1] = (f32x4){0.f, 0.f, 0.f, 0.f};

    auto stageA = [&](int k0, char* dst) {
        int row = w * 8 + (l >> 3);
        int scb = ((l & 7) << 4) ^ ((row & 7) << 4);
        gload_lds16(A + (size_t)(m0 + row) * K + k0 + (scb >> 1), dst + w * 1024);
    };
    auto stageB = [&](int k0, char* dst) {
#pragma unroll
        for (int p = 0; p < 2; ++p) {
            int c = w * 2 + p;
            int row = c * 8 + (l >> 3);
            int scb = ((l & 7) << 4) ^ ((row & 7) << 4);
            gload_lds16(Bt + (size_t)(n0 + row) * K + k0 + (scb >> 1), dst + c * 1024);
        }
    };

    int nkt = K / 64;
    stageA(0, sm); stageB(0, sm + 4096);
    stageA(64, sm + 12288); stageB(64, sm + 12288 + 4096);

    for (int kt = 0; kt < nkt; ++kt) {
        if (kt + 2 < nkt) {
            char* d = sm + ((kt + 2) % 3) * 12288;
            stageA((kt + 2) * 64, d);
            stageB((kt + 2) * 64, d + 4096);
        }
        int inflight = nkt - 1 - kt;
        if (inflight >= 2)      asm volatile("s_waitcnt vmcnt(6)" ::: "memory");
        else if (inflight == 1) asm volatile("s_waitcnt vmcnt(3)" ::: "memory");
        else                    asm volatile("s_waitcnt vmcnt(0)" ::: "memory");
        __builtin_amdgcn_s_barrier();

        const char* Ab = sm + (kt % 3) * 12288;
        const char* Bb = Ab + 4096;
#pragma unroll
        for (int kk = 0; kk < 2; ++kk) {
            short8t af;
            {
                int r = wm * 16 + (l & 15);
                int cb = (kk * 64 + (l >> 4) * 16) ^ ((r & 7) << 4);
                af = *(const short8t*)(Ab + r * 128 + cb);
            }
#pragma unroll
            for (int j = 0; j < 2; ++j) {
                int r = wn * 32 + j * 16 + (l & 15);
                int cb = (kk * 64 + (l >> 4) * 16) ^ ((r & 7) << 4);
                short8t bfv = *(const short8t*)(Bb + r * 128 + cb);
                acc[j] = __builtin_amdgcn_mfma_f32_16x16x32_bf16(af, bfv, acc[j], 0, 0, 0);
            }
        }
        __builtin_amdgcn_s_barrier();
    }

#pragma unroll
    for (int j = 0; j < 2; ++j) {
        int col = n0 + wn * 32 + j * 16 + (l & 15);
        int rowb = m0 + wm * 16 + (l >> 4) * 4;
#pragma unroll
        for (int r = 0; r < 4; ++r)
            C[(size_t)(rowb + r) * N + col] = acc[j][r];
    }
}

// conv+SiLU of 4 consecutive channels at one row; gl = seq position (causal clamp)
__device__ __forceinline__ float4 conv4(const float* __restrict__ prow, int gl, int zxcol,
                                        const float* __restrict__ conv_w,
                                        const float* __restrict__ conv_b) {
    float4 v2 = *(const float4*)(prow + zxcol);
    float4 v1 = make_float4(0.f, 0.f, 0.f, 0.f), v0 = v1;
    if (gl >= 1) v1 = *(const float4*)(prow - D_IN_PROJ + zxcol);
    if (gl >= 2) v0 = *(const float4*)(prow - 2 * D_IN_PROJ + zxcol);
    int ch = zxcol - D_INNER;
    float4 o;
    float a;
    a = conv_b[ch+0] + conv_w[(ch+0)*3]*v0.x + conv_w[(ch+0)*3+1]*v1.x + conv_w[(ch+0)*3+2]*v2.x;
    o.x = a / (1.f + __expf(-a));
    a = conv_b[ch+1] + conv_w[(ch+1)*3]*v0.y + conv_w[(ch+1)*3+1]*v1.y + conv_w[(ch+1)*3+2]*v2.y;
    o.y = a / (1.f + __expf(-a));
    a = conv_b[ch+2] + conv_w[(ch+2)*3]*v0.z + conv_w[(ch+2)*3+1]*v1.z + conv_w[(ch+2)*3+2]*v2.z;
    o.z = a / (1.f + __expf(-a));
    a = conv_b[ch+3] + conv_w[(ch+3)*3]*v0.w + conv_w[(ch+3)*3+1]*v1.w + conv_w[(ch+3)*3+2]*v2.w;
    o.w = a / (1.f + __expf(-a));
    return o;
}

// ---------------- SSD pass A (conv fused, MFMA; slim LDS: 4 buffers, P reuses Cs) ----------------
__global__ __launch_bounds__(256) void ssd_passA(const float* __restrict__ zxbcdt,
                                                 const float* __restrict__ conv_w,
                                                 const float* __restrict__ conv_b,
                                                 const float* __restrict__ dt_bias,
                                                 const float* __restrict__ A_log,
                                                 const float* __restrict__ D_param,
                                                 float* __restrict__ y,
                                                 float* __restrict__ Zbuf,
                                                 float* __restrict__ Ebuf) {
    int blk = blockIdx.x;          // b*128 + c*16 + h
    int h = blk & 15;
    int c = (blk >> 4) & 7;
    int b = blk >> 7;
    int tid = threadIdx.x;

    __shared__ __align__(16) unsigned short Cs_bf[QC][PB];   // C[t][n]; reused as P[t][s]
    __shared__ __align__(16) unsigned short Bs_bf[QC][PB];   // B[s][n]
    __shared__ __align__(16) unsigned short XDT_bf[QC][PB];  // XD^T[p][t]
    __shared__ __align__(16) unsigned short BTw_bf[QC][PB];  // (w·B)^T[n][t]
    __shared__ float csh[QC], dts[QC], wh[QC];
#define PS_bf Cs_bf

    int bl0 = b * L_SZ + c * QC;
    const float* zb = zxbcdt + (size_t)bl0 * D_IN_PROJ;

    // phase 1a: dt, cumsum, decays (wave 0)
    if (tid < 64) {
        int t = tid;
        float draw = zb[(size_t)t * D_IN_PROJ + 2 * D_INNER + 2 * D_STATE + h];
        float dtv = draw + dt_bias[h];
        dtv = (dtv > 20.f) ? dtv : log1pf(expf(dtv));
        float A = -expf(A_log[h]);
        float cs = A * dtv;
#pragma unroll
        for (int off = 1; off < 64; off <<= 1) {
            float tmp = __shfl_up(cs, off);
            if (t >= off) cs += tmp;
        }
        float cs63 = __shfl(cs, 63);
        dts[t] = dtv;
        csh[t] = cs;
        wh[t] = __expf(cs63 - cs);
        Ebuf[(((size_t)(b * NHEADS + h) * NCH) + c) * QC + t] = __expf(cs);
    }

    int row16 = tid >> 4;
    int col4 = (tid & 15) * 4;
    // phase 1b: conv B, C -> bf16
#pragma unroll
    for (int r = 0; r < 4; ++r) {
        int t = r * 16 + row16;
        int gl = c * QC + t;
        const float* prow = zb + (size_t)t * D_IN_PROJ;
        float4 Bv = conv4(prow, gl, D_INNER + D_INNER + col4, conv_w, conv_b);
        float4 Cv = conv4(prow, gl, D_INNER + D_INNER + D_STATE + col4, conv_w, conv_b);
        ushort4t bq = {f2bf(Bv.x), f2bf(Bv.y), f2bf(Bv.z), f2bf(Bv.w)};
        ushort4t cq = {f2bf(Cv.x), f2bf(Cv.y), f2bf(Cv.z), f2bf(Cv.w)};
        *(ushort4t*)&Bs_bf[t][col4] = bq;
        *(ushort4t*)&Cs_bf[t][col4] = cq;
    }
    __syncthreads();               // sync1: Bs/Cs/dts/wh visible

    // phase 2a: conv x -> XD^T; BTw from Bs (w folded)
#pragma unroll
    for (int r = 0; r < 4; ++r) {
        int t = r * 16 + row16;
        int gl = c * QC + t;
        const float* prow = zb + (size_t)t * D_IN_PROJ;
        float4 xv = conv4(prow, gl, D_INNER + h * HEAD_DIM + col4, conv_w, conv_b);
        float d = dts[t], wt = wh[t];
        xv.x *= d; xv.y *= d; xv.z *= d; xv.w *= d;
        ushort4t xq = {f2bf(xv.x), f2bf(xv.y), f2bf(xv.z), f2bf(xv.w)};
        ushort4t bq = *(ushort4t*)&Bs_bf[t][col4];
#pragma unroll
        for (int q = 0; q < 4; ++q) {
            XDT_bf[col4 + q][t] = xq[q];
            BTw_bf[col4 + q][t] = f2bf(bf2f(bq[q]) * wt);
        }
    }
    __syncthreads();               // sync2: XDT/BTw visible

    int l = tid & 63, wv = tid >> 6;
    int wm = wv >> 1, wn = wv & 1;
    int fr = l & 15, fq = l >> 4;

    f32x4 g[2][2];
    {   // G = C·B^T via MFMA
#pragma unroll
        for (int i = 0; i < 2; ++i)
#pragma unroll
            for (int j = 0; j < 2; ++j) g[i][j] = (f32x4){0.f, 0.f, 0.f, 0.f};
#pragma unroll
        for (int kk = 0; kk < 2; ++kk) {
            short8t af[2], bb[2];
#pragma unroll
            for (int i = 0; i < 2; ++i)
                af[i] = *(const short8t*)&Cs_bf[wm * 32 + i * 16 + fr][kk * 32 + fq * 8];
#pragma unroll
            for (int j = 0; j < 2; ++j)
                bb[j] = *(const short8t*)&Bs_bf[wn * 32 + j * 16 + fr][kk * 32 + fq * 8];
#pragma unroll
            for (int i = 0; i < 2; ++i)
#pragma unroll
                for (int j = 0; j < 2; ++j)
                    g[i][j] = __builtin_amdgcn_mfma_f32_16x16x32_bf16(af[i], bb[j], g[i][j], 0, 0, 0);
        }
    }
    __syncthreads();               // sync3: all waves done reading Cs -> safe to overwrite with P

    {   // mask+decay -> P (into Cs region)
#pragma unroll
        for (int i = 0; i < 2; ++i)
#pragma unroll
            for (int j = 0; j < 2; ++j) {
                int s = wn * 32 + j * 16 + fr;
                float css = csh[s];
#pragma unroll
                for (int r = 0; r < 4; ++r) {
                    int t = wm * 32 + i * 16 + fq * 4 + r;
                    float v = (s <= t) ? g[i][j][r] * __expf(csh[t] - css) : 0.f;
                    PS_bf[t][s] = f2bf(v);
                }
            }
    }
    __syncthreads();               // sync4: P visible

    {   // Y = P·XD via MFMA; epilogue + D·x
        f32x4 yv[2][2];
#pragma unroll
        for (int i = 0; i < 2; ++i)
#pragma unroll
            for (int j = 0; j < 2; ++j) yv[i][j] = (f32x4){0.f, 0.f, 0.f, 0.f};
#pragma unroll
        for (int kk = 0; kk < 2; ++kk) {
            short8t af[2], bb[2];
#pragma unroll
            for (int i = 0; i < 2; ++i)
                af[i] = *(const short8t*)&PS_bf[wm * 32 + i * 16 + fr][kk * 32 + fq * 8];
#pragma unroll
            for (int j = 0; j < 2; ++j)
                bb[j] = *(const short8t*)&XDT_bf[wn * 32 + j * 16 + fr][kk * 32 + fq * 8];
#pragma unroll
            for (int i = 0; i < 2; ++i)
#pragma unroll
                for (int j = 0; j < 2; ++j)
                    yv[i][j] = __builtin_amdgcn_mfma_f32_16x16x32_bf16(af[i], bb[j], yv[i][j], 0, 0, 0);
        }
        float Dp = D_param[h];
#pragma unroll
        for (int i = 0; i < 2; ++i)
#pragma unroll
            for (int j = 0; j < 2; ++j) {
                int p = wn * 32 + j * 16 + fr;
#pragma unroll
                for (int r = 0; r < 4; ++r) {
                    int t = wm * 32 + i * 16 + fq * 4 + r;
                    float xval = bf2f(XDT_bf[p][t]);
                    float fct = Dp / dts[t];
                    y[(size_t)(bl0 + t) * D_INNER + h * HEAD_DIM + p] =
                        yv[i][j][r] + fct * xval;
                }
            }
    }

    {   // Z = XD^T·(w·B) via MFMA -> Zbuf
        f32x4 zv[2][2];
#pragma unroll
        for (int i = 0; i < 2; ++i)
#pragma unroll
            for (int j = 0; j < 2; ++j) zv[i][j] = (f32x4){0.f, 0.f, 0.f, 0.f};
#pragma unroll
        for (int kk = 0; kk < 2; ++kk) {
            short8t af[2], bb[2];
#pragma unroll
            for (int i = 0; i < 2; ++i)
                af[i] = *(const short8t*)&XDT_bf[wm * 32 + i * 16 + fr][kk * 32 + fq * 8];
#pragma unroll
            for (int j = 0; j < 2; ++j)
                bb[j] = *(const short8t*)&BTw_bf[wn * 32 + j * 16 + fr][kk * 32 + fq * 8];
#pragma unroll
            for (int i = 0; i < 2; ++i)
#pragma unroll
                for (int j = 0; j < 2; ++j)
                    zv[i][j] = __builtin_amdgcn_mfma_f32_16x16x32_bf16(af[i], bb[j], zv[i][j], 0, 0, 0);
        }
        float* Zr = Zbuf + (((size_t)(b * NHEADS + h) * NCH) + c) * (HEAD_DIM * D_STATE);
#pragma unroll
        for (int i = 0; i < 2; ++i)
#pragma unroll
            for (int j = 0; j < 2; ++j) {
                int n = wn * 32 + j * 16 + fr;
#pragma unroll
                for (int r = 0; r < 4; ++r) {
                    int p = wm * 32 + i * 16 + fq * 4 + r;
                    Zr[p * D_STATE + n] = zv[i][j][r];
                }
            }
    }
#undef PS_bf
}

// ---------------- SSD pass C (passB folded; 224 blocks, c>=1 only) ----------------
__global__ __launch_bounds__(256) void ssd_passC(const float* __restrict__ zxbcdt,
                                                 const float* __restrict__ conv_w,
                                                 const float* __restrict__ conv_b,
                                                 const float* __restrict__ Zbuf,
                                                 const float* __restrict__ Ebuf,
                                                 float* __restrict__ y) {
    int blk = blockIdx.x;          // 224 = 16h * 7c * 2b
    int h = blk & 15;
    int q = blk >> 4;              // 0..13
    int c = 1 + (q % 7);
    int b = q / 7;
    int tid = threadIdx.x;

    __shared__ __align__(16) unsigned short Cs_bf[QC][PB];
    __shared__ __align__(16) unsigned short S_bf[QC][PB];
    __shared__ float Eh[QC];

    int bl0 = b * L_SZ + c * QC;
    const float* zb = zxbcdt + (size_t)bl0 * D_IN_PROJ;
    const float* Zb = Zbuf + ((size_t)(b * NHEADS + h) * NCH) * (HEAD_DIM * D_STATE);
    const float* Eb = Ebuf + ((size_t)(b * NHEADS + h) * NCH) * QC;

    {
        int p = tid >> 2, nq = (tid & 3) * 16;
        float S16[16];
#pragma unroll
        for (int qq = 0; qq < 16; ++qq) S16[qq] = 0.f;
        float wgt = 1.f;
        for (int j = c - 1; j >= 0; --j) {
            const float* Zj = Zb + (size_t)j * (HEAD_DIM * D_STATE) + p * D_STATE + nq;
#pragma unroll
            for (int q4 = 0; q4 < 4; ++q4) {
                float4 z = *(const float4*)(Zj + q4 * 4);
                S16[q4 * 4 + 0] += wgt * z.x;
                S16[q4 * 4 + 1] += wgt * z.y;
                S16[q4 * 4 + 2] += wgt * z.z;
                S16[q4 * 4 + 3] += wgt * z.w;
            }
            wgt *= Eb[(size_t)j * QC + 63];
        }
#pragma unroll
        for (int q4 = 0; q4 < 4; ++q4) {
            ushort4t s4 = {f2bf(S16[q4 * 4 + 0]), f2bf(S16[q4 * 4 + 1]),
                           f2bf(S16[q4 * 4 + 2]), f2bf(S16[q4 * 4 + 3])};
            *(ushort4t*)&S_bf[p][nq + q4 * 4] = s4;
        }
    }

    int row16 = tid >> 4, col4 = (tid & 15) * 4;
#pragma unroll
    for (int r = 0; r < 4; ++r) {
        int t = r * 16 + row16;
        int gl = c * QC + t;
        float4 Cv = conv4(zb + (size_t)t * D_IN_PROJ, gl,
                          D_INNER + D_INNER + D_STATE + col4, conv_w, conv_b);
        ushort4t cq = {f2bf(Cv.x), f2bf(Cv.y), f2bf(Cv.z), f2bf(Cv.w)};
        *(ushort4t*)&Cs_bf[t][col4] = cq;
    }
    if (tid < 64)
        Eh[tid] = Ebuf[(((size_t)(b * NHEADS + h) * NCH) + c) * QC + tid];
    __syncthreads();

    int l = tid & 63, wv = tid >> 6;
    int wm = wv >> 1, wn = wv & 1;
    int fr = l & 15, fq = l >> 4;
    f32x4 acc[2][2];
#pragma unroll
    for (int i = 0; i < 2; ++i)
#pragma unroll
        for (int j = 0; j < 2; ++j) acc[i][j] = (f32x4){0.f, 0.f, 0.f, 0.f};
#pragma unroll
    for (int kk = 0; kk < 2; ++kk) {
        short8t af[2], bb[2];
#pragma unroll
        for (int i = 0; i < 2; ++i)
            af[i] = *(const short8t*)&Cs_bf[wm * 32 + i * 16 + fr][kk * 32 + fq * 8];
#pragma unroll
        for (int j = 0; j < 2; ++j)
            bb[j] = *(const short8t*)&S_bf[wn * 32 + j * 16 + fr][kk * 32 + fq * 8];
#pragma unroll
        for (int i = 0; i < 2; ++i)
#pragma unroll
            for (int j = 0; j < 2; ++j)
                acc[i][j] = __builtin_amdgcn_mfma_f32_16x16x32_bf16(af[i], bb[j], acc[i][j], 0, 0, 0);
    }
#pragma unroll
    for (int i = 0; i < 2; ++i)
#pragma unroll
        for (int j = 0; j < 2; ++j) {
            int p = wn * 32 + j * 16 + fr;
#pragma unroll
            for (int r = 0; r < 4; ++r) {
                int t = wm * 32 + i * 16 + fq * 4 + r;
                float* yp = y + (size_t)(bl0 + t) * D_INNER + h * HEAD_DIM + p;
                *yp += Eh[t] * acc[i][j][r];
            }
        }
}

// ---------------- gate (SiLU(z)) + RMSNorm -> bf16 ----------------
__global__ __launch_bounds__(256) void gated_rmsnorm_kernel(const float* __restrict__ zxbcdt,
                                                            const float* __restrict__ y,
                                                            const float* __restrict__ rms_w,
                                                            unsigned short* __restrict__ yn_bf) {
    int bl = blockIdx.x;
    int tid = threadIdx.x;
    __shared__ float red[4];
    __shared__ float sscale;
    float vals[4];
    float sumsq = 0.f;
#pragma unroll
    for (int i = 0; i < 4; ++i) {
        int col = tid + i * 256;
        float yv = y[(size_t)bl * D_INNER + col];
        float z = zxbcdt[(size_t)bl * D_IN_PROJ + col];
        float yz = yv * (z / (1.f + expf(-z)));
        vals[i] = yz;
        sumsq += yz * yz;
    }
#pragma unroll
    for (int off = 32; off; off >>= 1) sumsq += __shfl_xor(sumsq, off);
    int wave = tid >> 6, lane = tid & 63;
    if (lane == 0) red[wave] = sumsq;
    __syncthreads();
    if (tid == 0) {
        float t = red[0] + red[1] + red[2] + red[3];
        sscale = rsqrtf(t / (float)D_INNER + RMS_EPS);
    }
    __syncthreads();
    float sc = sscale;
#pragma unroll
    for (int i = 0; i < 4; ++i) {
        int col = tid + i * 256;
        yn_bf[(size_t)bl * D_INNER + col] = f2bf(vals[i] * sc * rms_w[col]);
    }
}

// ---------------- launch ----------------
extern "C" void kernel_launch(void* const* d_in, const int* in_sizes, int n_in,
                              void* d_out, int out_size, void* d_ws, size_t ws_size,
                              hipStream_t stream) {
    const float* u       = (const float*)d_in[0];
    const float* W_in    = (const float*)d_in[1];
    const float* conv_w  = (const float*)d_in[2];
    const float* conv_b  = (const float*)d_in[3];
    const float* dt_bias = (const float*)d_in[4];
    const float* A_log   = (const float*)d_in[5];
    const float* D_param = (const float*)d_in[6];
    const float* rms_w   = (const float*)d_in[7];
    const float* W_out   = (const float*)d_in[8];
    float* out = (float*)d_out;

    float* ws = (float*)d_ws;
    float* zxbcdt = ws;                                    // [1024][2192] f32
    float* y      = zxbcdt + (size_t)BL * D_IN_PROJ;       // [1024][1024] f32
    float* Zbuf   = y + (size_t)BL * D_INNER;              // [32][8][64][64] f32
    float* Ebuf   = Zbuf + (size_t)32 * NCH * 4096;        // [32][8][64] f32
    unsigned short* u_bf  = (unsigned short*)(Ebuf + 32 * NCH * QC);   // [1024][512]
    unsigned short* Wt1   = u_bf + (size_t)BL * D_MODEL;               // [2304][512]
    unsigned short* Wt2   = Wt1 + (size_t)NPAD1 * D_MODEL;             // [512][1024]
    unsigned short* yn_bf = Wt2 + (size_t)D_MODEL * D_INNER;           // [1024][1024]

    // 0) convert/transpose weights + u to bf16
    prep_kernel<<<672, 256, 0, stream>>>(W_in, W_out, u, Wt1, Wt2, u_bf);

    // 1) in_proj: zxbcdt = u @ W_in
    gemm_mfma64<<<dim3(NPAD1 / 64, BL / 64), 256, 0, stream>>>(
        u_bf, Wt1, zxbcdt, D_IN_PROJ, D_MODEL);

    // 2) SSD
    ssd_passA<<<B_SZ * NCH * NHEADS, 256, 0, stream>>>(
        zxbcdt, conv_w, conv_b, dt_bias, A_log, D_param, y, Zbuf, Ebuf);
    ssd_passC<<<224, 256, 0, stream>>>(
        zxbcdt, conv_w, conv_b, Zbuf, Ebuf, y);

    // 3) gate + RMSNorm -> bf16 (compact intermediate)
    gated_rmsnorm_kernel<<<BL, 256, 0, stream>>>(zxbcdt, y, rms_w, yn_bf);

    // 4) out_proj: out = yn @ W_out  (32x64 tiles, 256 blocks)
    gemm_mfma32<<<dim3(D_MODEL / 64, BL / 32), 256, 0, stream>>>(
        yn_bf, Wt2, out, D_MODEL, D_INNER);
}